// Round 5
// baseline (576.484 us; speedup 1.0000x reference)
//
#include <hip/hip_runtime.h>

#define D 64          // D_IN == D_OUT
#define D_EDGE 16
#define NEG 0.01f

typedef unsigned int  uint32;
typedef unsigned short ushort16;

// leaky = max(t, 0.01t): exact for both signs, 2 VALU ops
__device__ __forceinline__ float leaky(float v) { return fmaxf(v, NEG * v); }

// fp32 -> bf16 (round-to-nearest-even), and back (exact)
__device__ __forceinline__ ushort16 f2bf(float f) {
    uint32 b = __float_as_uint(f);
    uint32 r = b + 0x7fffu + ((b >> 16) & 1u);
    return (ushort16)(r >> 16);
}
__device__ __forceinline__ float bf2f(ushort16 u) {
    return __uint_as_float(((uint32)u) << 16);
}
__device__ __forceinline__ float bf_lo(uint32 w) { return __uint_as_float(w << 16); }
__device__ __forceinline__ float bf_hi(uint32 w) { return __uint_as_float(w & 0xffff0000u); }

// ---------------- Kernel 1: per-node precompute ----------------
//   xt[n] (bf16) = x[n] @ W2.T ; A[n] (bf16) = x[n] @ W1[:, :64].T
//   W rows wave-uniform (scalar loads); x staged coalesced via LDS; results
//   staged in LDS (stride-33) and written out coalesced (fixes the 20x HBM
//   write amplification measured in round 3: WRITE 523 MB -> ~26 MB).
__global__ __launch_bounds__(256) void node_kernel(
    const float* __restrict__ x, const float* __restrict__ W1,
    const float* __restrict__ W2,
    ushort16* __restrict__ Abf, ushort16* __restrict__ xtb, int N_)
{
    __shared__ float xs[64][68];               // 17408 B; reused for output staging
    uint32* sA = (uint32*)&xs[0][0];           // 64*33 dwords  (A = W1 part)
    uint32* sX = sA + 64 * 33;                 // 64*33 dwords  (xt = W2 part)

    const int tid = threadIdx.x;
    const int b0  = blockIdx.x * 64;

    // coalesced stage: 64 rows x 16 float4
    for (int idx = tid; idx < 64 * 16; idx += 256) {
        const int rr = idx >> 4, cc = idx & 15;
        float4 v = make_float4(0.f, 0.f, 0.f, 0.f);
        if (b0 + rr < N_) v = ((const float4*)(x + (size_t)(b0 + rr) * D))[cc];
        *(float4*)&xs[rr][cc * 4] = v;
    }
    __syncthreads();

    const int lane = tid & 63;
    const int q    = __builtin_amdgcn_readfirstlane(tid >> 6);   // wave-uniform

    float4 xr[16];
#pragma unroll
    for (int i = 0; i < 16; i++) xr[i] = *(const float4*)&xs[lane][4 * i];
    __syncthreads();    // xs re-used as sA/sX below; all reads must be done

    float a_prev = 0.f, b_prev = 0.f;
#pragma unroll
    for (int kk = 0; kk < 16; kk++) {
        const int k = q * 16 + kk;
        const float4* w2r = (const float4*)(W2 + (size_t)k * 64);   // uniform -> s_load
        const float4* w1r = (const float4*)(W1 + (size_t)k * 80);
        float a = 0.f, b = 0.f;
#pragma unroll
        for (int j = 0; j < 16; j++) {
            float4 w = w2r[j];
            a += xr[j].x * w.x + xr[j].y * w.y + xr[j].z * w.z + xr[j].w * w.w;
            float4 u = w1r[j];
            b += xr[j].x * u.x + xr[j].y * u.y + xr[j].z * u.z + xr[j].w * u.w;
        }
        if (kk & 1) {
            const int pr = k >> 1;    // global dword col 0..31
            sX[lane * 33 + pr] = (uint32)f2bf(a_prev) | ((uint32)f2bf(a) << 16);
            sA[lane * 33 + pr] = (uint32)f2bf(b_prev) | ((uint32)f2bf(b) << 16);
        } else {
            a_prev = a; b_prev = b;
        }
    }
    __syncthreads();

    // coalesced writeout
    uint32* Au = (uint32*)Abf;
    uint32* Xu = (uint32*)xtb;
    const size_t gbase = (size_t)b0 * 32;
    for (int base = tid * 4; base < 2048; base += 1024) {
        const int nn = base >> 5, cc = base & 31;
        if (b0 + nn < N_) {
            const uint32* ra = sA + nn * 33 + cc;
            const uint32* rx = sX + nn * 33 + cc;
            uint4 va = make_uint4(ra[0], ra[1], ra[2], ra[3]);
            uint4 vx = make_uint4(rx[0], rx[1], rx[2], rx[3]);
            *(uint4*)(Au + gbase + base) = va;
            *(uint4*)(Xu + gbase + base) = vx;
        }
    }
}

// ---------------- CSR build: histogram + single-block scan ----------------
__global__ __launch_bounds__(256) void hist_kernel(
    const int* __restrict__ dst, int* __restrict__ cnt, int E_)
{
    int i = blockIdx.x * 256 + threadIdx.x;
    if (i < E_) atomicAdd(cnt + dst[i], 1);
}

// exclusive scan of cnt[0..N) -> rowst, one workgroup of 1024 threads
// (replaces scan1+scan2+scan3: -2 dispatches of launch overhead)
__global__ __launch_bounds__(1024) void scan_kernel(
    const int* __restrict__ cnt, int* __restrict__ rowst, int N_)
{
    __shared__ int sm[1024];
    const int t = threadIdx.x;
    const int chunk = (N_ + 1023) / 1024;
    const int i0 = t * chunk;
    const int i1 = (i0 + chunk < N_) ? i0 + chunk : N_;

    int s = 0;
    for (int i = i0; i < i1; i++) s += cnt[i];
    sm[t] = s;
    __syncthreads();
    for (int off = 1; off < 1024; off <<= 1) {   // inclusive Hillis-Steele
        int a = (t >= off) ? sm[t - off] : 0;
        __syncthreads();
        sm[t] += a;
        __syncthreads();
    }
    int run = sm[t] - s;                         // exclusive prefix of chunk
    for (int i = i0; i < i1; i++) { rowst[i] = run; run += cnt[i]; }
}

// ---------------- Kernel 2: edge logits, ONE LANE PER EDGE ----------------
// KEY FIX (round 5): W1b + attn staged in LDS, read via broadcast ds_read.
// Previously the in-loop weight reads were global loads sharing the vmcnt
// queue with the 8 in-flight A-row gathers -> every j-iteration's weight
// wait also drained the gather queue (~300-600 cy exposed per iter,
// VALUBusy 35%). LDS weights are lgkm-counted broadcasts (~30 cy, hidden
// under the 76 cy of FMA per iteration); the gather queue now drains
// head-only, once per edge.
__global__ __launch_bounds__(256) void edge_kernel(
    const float* __restrict__ edge_attr, const int* __restrict__ src,
    const int* __restrict__ dst, const float* __restrict__ W1,
    const float* __restrict__ attn, const ushort16* __restrict__ Abf,
    int* __restrict__ rowpos, int2* __restrict__ SP, int E_)
{
    __shared__ float ws[64 * 16];   // W1 rows 0..63, cols 64..79, [k][16]
    __shared__ float as[64];
    const int tid = threadIdx.x;
    for (int i = tid; i < 64 * 16; i += 256) {
        const int k = i >> 4, c = i & 15;
        ws[i] = W1[k * 80 + 64 + c];
    }
    if (tid < 64) as[tid] = attn[tid];
    __syncthreads();

    const int e = blockIdx.x * 256 + tid;
    if (e >= E_) return;

    const int s = src[e];
    const int d = dst[e];

    // this lane's A row: 64 bf16 = 32 packed dwords (128 B = 1 line), gather
    uint32 Ad[32];
    {
        const uint4* Ap = (const uint4*)(Abf + (size_t)s * D);
#pragma unroll
        for (int i = 0; i < 8; i++) *(uint4*)(Ad + 4 * i) = Ap[i];
    }
    // this lane's edge_attr row: 16 f32 (64 B), dense across lanes
    float Ef[16];
    {
        const float4* Ep = (const float4*)(edge_attr + (size_t)e * D_EDGE);
#pragma unroll
        for (int i = 0; i < 4; i++) *(float4*)(Ef + 4 * i) = Ep[i];
    }

    float v = 0.f;
#pragma unroll
    for (int j = 0; j < 32; ++j) {          // packed dword j -> channels 2j, 2j+1
        const float4* w0 = (const float4*)(ws + (2 * j) * 16);      // LDS broadcast
        const float4* w1 = (const float4*)(ws + (2 * j + 1) * 16);
        float4 p0 = w0[0], p1 = w0[1], p2 = w0[2], p3 = w0[3];
        float4 q0 = w1[0], q1 = w1[1], q2 = w1[2], q3 = w1[3];

        float g0 = bf_lo(Ad[j]);            // A[s][2j]
        float g1 = bf_hi(Ad[j]);            // A[s][2j+1]

        g0 = fmaf(Ef[ 0], p0.x, g0); g1 = fmaf(Ef[ 0], q0.x, g1);
        g0 = fmaf(Ef[ 1], p0.y, g0); g1 = fmaf(Ef[ 1], q0.y, g1);
        g0 = fmaf(Ef[ 2], p0.z, g0); g1 = fmaf(Ef[ 2], q0.z, g1);
        g0 = fmaf(Ef[ 3], p0.w, g0); g1 = fmaf(Ef[ 3], q0.w, g1);
        g0 = fmaf(Ef[ 4], p1.x, g0); g1 = fmaf(Ef[ 4], q1.x, g1);
        g0 = fmaf(Ef[ 5], p1.y, g0); g1 = fmaf(Ef[ 5], q1.y, g1);
        g0 = fmaf(Ef[ 6], p1.z, g0); g1 = fmaf(Ef[ 6], q1.z, g1);
        g0 = fmaf(Ef[ 7], p1.w, g0); g1 = fmaf(Ef[ 7], q1.w, g1);
        g0 = fmaf(Ef[ 8], p2.x, g0); g1 = fmaf(Ef[ 8], q2.x, g1);
        g0 = fmaf(Ef[ 9], p2.y, g0); g1 = fmaf(Ef[ 9], q2.y, g1);
        g0 = fmaf(Ef[10], p2.z, g0); g1 = fmaf(Ef[10], q2.z, g1);
        g0 = fmaf(Ef[11], p2.w, g0); g1 = fmaf(Ef[11], q2.w, g1);
        g0 = fmaf(Ef[12], p3.x, g0); g1 = fmaf(Ef[12], q3.x, g1);
        g0 = fmaf(Ef[13], p3.y, g0); g1 = fmaf(Ef[13], q3.y, g1);
        g0 = fmaf(Ef[14], p3.z, g0); g1 = fmaf(Ef[14], q3.z, g1);
        g0 = fmaf(Ef[15], p3.w, g0); g1 = fmaf(Ef[15], q3.w, g1);

        v = fmaf(leaky(g0), as[2 * j],     v);
        v = fmaf(leaky(g1), as[2 * j + 1], v);
    }

    const float p = __expf(v);
    const int pos = atomicAdd(rowpos + d, 1);
    SP[pos] = make_int2(s, __float_as_int(p));
}

// ---------------- Kernel 3: per-node CSR aggregation + normalize + bias --------
__global__ __launch_bounds__(256) void agg_kernel(
    const ushort16* __restrict__ xtb, const int2* __restrict__ SP,
    const int* __restrict__ rowend, const float* __restrict__ bias,
    float* __restrict__ out, int N_)
{
    const int n    = blockIdx.x * 4 + (threadIdx.x >> 6);
    const int lane = threadIdx.x & 63;
    if (n >= N_) return;
    const int half = lane >> 5;
    const int c    = lane & 31;

    const int end   = rowend[n];
    const int start = n ? rowend[n - 1] : 0;
    const uint32* X = (const uint32*)xtb;    // dword idx = row*32 + c

    float accx = 0.f, accy = 0.f, den = 0.f;
    int i = start;
    for (; i + 7 < end; i += 8) {
        int2 A0 = SP[i+0], A1 = SP[i+1], A2 = SP[i+2], A3 = SP[i+3];
        int2 A4 = SP[i+4], A5 = SP[i+5], A6 = SP[i+6], A7 = SP[i+7];
        int   r0 = half ? A1.x : A0.x;  float p0 = __int_as_float(half ? A1.y : A0.y);
        int   r1 = half ? A3.x : A2.x;  float p1 = __int_as_float(half ? A3.y : A2.y);
        int   r2 = half ? A5.x : A4.x;  float p2 = __int_as_float(half ? A5.y : A4.y);
        int   r3 = half ? A7.x : A6.x;  float p3 = __int_as_float(half ? A7.y : A6.y);
        uint32 u0 = X[(size_t)r0 * 32 + c];
        uint32 u1 = X[(size_t)r1 * 32 + c];
        uint32 u2 = X[(size_t)r2 * 32 + c];
        uint32 u3 = X[(size_t)r3 * 32 + c];
        accx = fmaf(p0, bf_lo(u0), accx); accy = fmaf(p0, bf_hi(u0), accy);
        accx = fmaf(p1, bf_lo(u1), accx); accy = fmaf(p1, bf_hi(u1), accy);
        accx = fmaf(p2, bf_lo(u2), accx); accy = fmaf(p2, bf_hi(u2), accy);
        accx = fmaf(p3, bf_lo(u3), accx); accy = fmaf(p3, bf_hi(u3), accy);
        den += (p0 + p1) + (p2 + p3);
    }
    for (; i < end; i++) {                 // <=7 leftovers: low half only
        int2 a = SP[i];
        if (half == 0) {
            float p = __int_as_float(a.y);
            uint32 u = X[(size_t)a.x * 32 + c];
            accx = fmaf(p, bf_lo(u), accx);
            accy = fmaf(p, bf_hi(u), accy);
            den += p;
        }
    }
    accx += __shfl_xor(accx, 32, 64);
    accy += __shfl_xor(accy, 32, 64);
    den  += __shfl_xor(den,  32, 64);

    if (half == 0) {
        const float sc = den > 0.f ? 1.f / den : 0.f;
        const float2 bb = *(const float2*)(bias + 2 * c);
        float2 o;
        o.x = fmaf(accx, sc, bb.x);
        o.y = fmaf(accy, sc, bb.y);
        *(float2*)(out + (size_t)n * D + 2 * c) = o;
    }
}

extern "C" void kernel_launch(void* const* d_in, const int* in_sizes, int n_in,
                              void* d_out, int out_size, void* d_ws, size_t ws_size,
                              hipStream_t stream)
{
    const float* x         = (const float*)d_in[0];
    const float* edge_attr = (const float*)d_in[1];
    const int*   src       = (const int*)d_in[2];
    const int*   dst       = (const int*)d_in[3];
    const float* W1        = (const float*)d_in[4];
    const float* W2        = (const float*)d_in[5];
    const float* attn      = (const float*)d_in[6];
    const float* bias      = (const float*)d_in[7];
    float* out = (float*)d_out;

    const int N_ = in_sizes[0] / D;   // 100000
    const int E_ = in_sizes[2];       // 1280000

    // workspace (~36.7 MB):
    //   Abf[N*64] bf16 | xtb[N*64] bf16 | SP[E] int2 | rowst[N] | cnt[N]
    char* w = (char*)d_ws;
    ushort16* Abf  = (ushort16*)w;  w += (size_t)N_ * D * sizeof(ushort16);
    ushort16* xtb  = (ushort16*)w;  w += (size_t)N_ * D * sizeof(ushort16);
    int2*     SP   = (int2*)w;      w += (size_t)E_ * sizeof(int2);
    int*      rowst= (int*)w;       w += (size_t)N_ * sizeof(int);
    int*      cnt  = (int*)w;

    hipMemsetAsync(cnt, 0, (size_t)N_ * sizeof(int), stream);

    hist_kernel<<<(E_ + 255) / 256, 256, 0, stream>>>(dst, cnt, E_);
    scan_kernel<<<1, 1024, 0, stream>>>(cnt, rowst, N_);

    node_kernel<<<(N_ + 63) / 64, 256, 0, stream>>>(x, W1, W2, Abf, xtb, N_);

    edge_kernel<<<(E_ + 255) / 256, 256, 0, stream>>>(edge_attr, src, dst, W1,
                                                      attn, Abf, rowst, SP, E_);

    agg_kernel<<<(N_ + 3) / 4, 256, 0, stream>>>(xtb, SP, rowst, bias, out, N_);
}

// Round 7
// 426.327 us; speedup vs baseline: 1.3522x; 1.3522x over previous
//
#include <hip/hip_runtime.h>

#define D 64          // D_IN == D_OUT
#define D_EDGE 16
#define NEG 0.01f

typedef unsigned int  uint32;
typedef unsigned short ushort16;

// leaky = max(t, 0.01t): exact for both signs, 2 VALU ops
__device__ __forceinline__ float leaky(float v) { return fmaxf(v, NEG * v); }

// fp32 -> bf16 (round-to-nearest-even), and back (exact)
__device__ __forceinline__ ushort16 f2bf(float f) {
    uint32 b = __float_as_uint(f);
    uint32 r = b + 0x7fffu + ((b >> 16) & 1u);
    return (ushort16)(r >> 16);
}
__device__ __forceinline__ float bf2f(ushort16 u) {
    return __uint_as_float(((uint32)u) << 16);
}
__device__ __forceinline__ float bf_lo(uint32 w) { return __uint_as_float(w << 16); }
__device__ __forceinline__ float bf_hi(uint32 w) { return __uint_as_float(w & 0xffff0000u); }

// ---------------- Kernel 1: per-node precompute ----------------
//   xt[n] (bf16) = x[n] @ W2.T ; A[n] (bf16) = x[n] @ W1[:, :64].T
//   W rows wave-uniform (scalar loads); x staged coalesced via LDS; results
//   staged in LDS (stride-33) and written out coalesced (fixes the 20x HBM
//   write amplification measured in round 3: WRITE 523 MB -> ~26 MB).
__global__ __launch_bounds__(256) void node_kernel(
    const float* __restrict__ x, const float* __restrict__ W1,
    const float* __restrict__ W2,
    ushort16* __restrict__ Abf, ushort16* __restrict__ xtb, int N_)
{
    __shared__ float xs[64][68];               // 17408 B; reused for output staging
    uint32* sA = (uint32*)&xs[0][0];           // 64*33 dwords  (A = W1 part)
    uint32* sX = sA + 64 * 33;                 // 64*33 dwords  (xt = W2 part)

    const int tid = threadIdx.x;
    const int b0  = blockIdx.x * 64;

    // coalesced stage: 64 rows x 16 float4
    for (int idx = tid; idx < 64 * 16; idx += 256) {
        const int rr = idx >> 4, cc = idx & 15;
        float4 v = make_float4(0.f, 0.f, 0.f, 0.f);
        if (b0 + rr < N_) v = ((const float4*)(x + (size_t)(b0 + rr) * D))[cc];
        *(float4*)&xs[rr][cc * 4] = v;
    }
    __syncthreads();

    const int lane = tid & 63;
    const int q    = __builtin_amdgcn_readfirstlane(tid >> 6);   // wave-uniform

    float4 xr[16];
#pragma unroll
    for (int i = 0; i < 16; i++) xr[i] = *(const float4*)&xs[lane][4 * i];
    __syncthreads();    // xs re-used as sA/sX below; all reads must be done

    float a_prev = 0.f, b_prev = 0.f;
#pragma unroll
    for (int kk = 0; kk < 16; kk++) {
        const int k = q * 16 + kk;
        const float4* w2r = (const float4*)(W2 + (size_t)k * 64);   // uniform -> s_load
        const float4* w1r = (const float4*)(W1 + (size_t)k * 80);
        float a = 0.f, b = 0.f;
#pragma unroll
        for (int j = 0; j < 16; j++) {
            float4 w = w2r[j];
            a += xr[j].x * w.x + xr[j].y * w.y + xr[j].z * w.z + xr[j].w * w.w;
            float4 u = w1r[j];
            b += xr[j].x * u.x + xr[j].y * u.y + xr[j].z * u.z + xr[j].w * u.w;
        }
        if (kk & 1) {
            const int pr = k >> 1;    // global dword col 0..31
            sX[lane * 33 + pr] = (uint32)f2bf(a_prev) | ((uint32)f2bf(a) << 16);
            sA[lane * 33 + pr] = (uint32)f2bf(b_prev) | ((uint32)f2bf(b) << 16);
        } else {
            a_prev = a; b_prev = b;
        }
    }
    __syncthreads();

    // coalesced writeout
    uint32* Au = (uint32*)Abf;
    uint32* Xu = (uint32*)xtb;
    const size_t gbase = (size_t)b0 * 32;
    for (int base = tid * 4; base < 2048; base += 1024) {
        const int nn = base >> 5, cc = base & 31;
        if (b0 + nn < N_) {
            const uint32* ra = sA + nn * 33 + cc;
            const uint32* rx = sX + nn * 33 + cc;
            uint4 va = make_uint4(ra[0], ra[1], ra[2], ra[3]);
            uint4 vx = make_uint4(rx[0], rx[1], rx[2], rx[3]);
            *(uint4*)(Au + gbase + base) = va;
            *(uint4*)(Xu + gbase + base) = vx;
        }
    }
}

// ---------------- CSR build: histogram + 3-kernel exclusive scan ----------------
// (round-5's single-WG fused scan was 161 us: one CU, serial 98-element
//  chunks, uncoalesced lanes. The 3-kernel grid-parallel scan is ~10 us.)
__global__ __launch_bounds__(256) void hist_kernel(
    const int* __restrict__ dst, int* __restrict__ cnt, int E_)
{
    int i = blockIdx.x * 256 + threadIdx.x;
    if (i < E_) atomicAdd(cnt + dst[i], 1);
}

__global__ __launch_bounds__(256) void scan1(
    const int* __restrict__ cnt, int* __restrict__ part, int N_)
{
    __shared__ int sm[256];
    const int b = blockIdx.x, t = threadIdx.x;
    const int i0 = b * 1024 + t * 4;
    int s = 0;
    if (i0     < N_) s += cnt[i0];
    if (i0 + 1 < N_) s += cnt[i0 + 1];
    if (i0 + 2 < N_) s += cnt[i0 + 2];
    if (i0 + 3 < N_) s += cnt[i0 + 3];
    sm[t] = s; __syncthreads();
    for (int off = 128; off > 0; off >>= 1) {
        if (t < off) sm[t] += sm[t + off];
        __syncthreads();
    }
    if (t == 0) part[b] = sm[0];
}

__global__ __launch_bounds__(256) void scan2(int* __restrict__ part, int nb)
{
    __shared__ int sm[256];
    const int t = threadIdx.x;
    int v = (t < nb) ? part[t] : 0;
    sm[t] = v; __syncthreads();
    for (int off = 1; off < 256; off <<= 1) {
        int a = (t >= off) ? sm[t - off] : 0;
        __syncthreads();
        sm[t] += a;
        __syncthreads();
    }
    if (t < nb) part[t] = sm[t] - v;   // exclusive prefix of block sums
}

__global__ __launch_bounds__(256) void scan3(
    const int* __restrict__ cnt, const int* __restrict__ part,
    int* __restrict__ rowst, int N_)
{
    __shared__ int sm[256];
    const int b = blockIdx.x, t = threadIdx.x;
    const int i0 = b * 1024 + t * 4;
    int c0 = 0, c1 = 0, c2 = 0, c3 = 0;
    if (i0     < N_) c0 = cnt[i0];
    if (i0 + 1 < N_) c1 = cnt[i0 + 1];
    if (i0 + 2 < N_) c2 = cnt[i0 + 2];
    if (i0 + 3 < N_) c3 = cnt[i0 + 3];
    const int s = c0 + c1 + c2 + c3;
    sm[t] = s; __syncthreads();
    for (int off = 1; off < 256; off <<= 1) {
        int a = (t >= off) ? sm[t - off] : 0;
        __syncthreads();
        sm[t] += a;
        __syncthreads();
    }
    const int base = part[b] + (sm[t] - s);
    if (i0     < N_) rowst[i0]     = base;
    if (i0 + 1 < N_) rowst[i0 + 1] = base + c0;
    if (i0 + 2 < N_) rowst[i0 + 2] = base + c0 + c1;
    if (i0 + 3 < N_) rowst[i0 + 3] = base + c0 + c1 + c2;
}

// ---------------- Kernel 2: edge logits, ONE LANE PER EDGE ----------------
// W1b + attn staged in LDS (broadcast ds_read, lgkm-counted) so the vmcnt
// queue carries only the 8 A-row gathers + edge_attr loads. Measuring this
// variant this round: if dur >= 118 us the LDS theory is falsified.
__global__ __launch_bounds__(256) void edge_kernel(
    const float* __restrict__ edge_attr, const int* __restrict__ src,
    const int* __restrict__ dst, const float* __restrict__ W1,
    const float* __restrict__ attn, const ushort16* __restrict__ Abf,
    int* __restrict__ rowpos, int2* __restrict__ SP, int E_)
{
    __shared__ float ws[64 * 16];   // W1 rows 0..63, cols 64..79, [k][16]
    __shared__ float as[64];
    const int tid = threadIdx.x;
    for (int i = tid; i < 64 * 16; i += 256) {
        const int k = i >> 4, c = i & 15;
        ws[i] = W1[k * 80 + 64 + c];
    }
    if (tid < 64) as[tid] = attn[tid];
    __syncthreads();

    const int e = blockIdx.x * 256 + tid;
    if (e >= E_) return;

    const int s = src[e];
    const int d = dst[e];

    // this lane's A row: 64 bf16 = 32 packed dwords (128 B = 1 line), gather
    uint32 Ad[32];
    {
        const uint4* Ap = (const uint4*)(Abf + (size_t)s * D);
#pragma unroll
        for (int i = 0; i < 8; i++) *(uint4*)(Ad + 4 * i) = Ap[i];
    }
    // this lane's edge_attr row: 16 f32 (64 B), dense across lanes
    float Ef[16];
    {
        const float4* Ep = (const float4*)(edge_attr + (size_t)e * D_EDGE);
#pragma unroll
        for (int i = 0; i < 4; i++) *(float4*)(Ef + 4 * i) = Ep[i];
    }

    float v = 0.f;
#pragma unroll
    for (int j = 0; j < 32; ++j) {          // packed dword j -> channels 2j, 2j+1
        const float4* w0 = (const float4*)(ws + (2 * j) * 16);      // LDS broadcast
        const float4* w1 = (const float4*)(ws + (2 * j + 1) * 16);
        float4 p0 = w0[0], p1 = w0[1], p2 = w0[2], p3 = w0[3];
        float4 q0 = w1[0], q1 = w1[1], q2 = w1[2], q3 = w1[3];

        float g0 = bf_lo(Ad[j]);            // A[s][2j]
        float g1 = bf_hi(Ad[j]);            // A[s][2j+1]

        g0 = fmaf(Ef[ 0], p0.x, g0); g1 = fmaf(Ef[ 0], q0.x, g1);
        g0 = fmaf(Ef[ 1], p0.y, g0); g1 = fmaf(Ef[ 1], q0.y, g1);
        g0 = fmaf(Ef[ 2], p0.z, g0); g1 = fmaf(Ef[ 2], q0.z, g1);
        g0 = fmaf(Ef[ 3], p0.w, g0); g1 = fmaf(Ef[ 3], q0.w, g1);
        g0 = fmaf(Ef[ 4], p1.x, g0); g1 = fmaf(Ef[ 4], q1.x, g1);
        g0 = fmaf(Ef[ 5], p1.y, g0); g1 = fmaf(Ef[ 5], q1.y, g1);
        g0 = fmaf(Ef[ 6], p1.z, g0); g1 = fmaf(Ef[ 6], q1.z, g1);
        g0 = fmaf(Ef[ 7], p1.w, g0); g1 = fmaf(Ef[ 7], q1.w, g1);
        g0 = fmaf(Ef[ 8], p2.x, g0); g1 = fmaf(Ef[ 8], q2.x, g1);
        g0 = fmaf(Ef[ 9], p2.y, g0); g1 = fmaf(Ef[ 9], q2.y, g1);
        g0 = fmaf(Ef[10], p2.z, g0); g1 = fmaf(Ef[10], q2.z, g1);
        g0 = fmaf(Ef[11], p2.w, g0); g1 = fmaf(Ef[11], q2.w, g1);
        g0 = fmaf(Ef[12], p3.x, g0); g1 = fmaf(Ef[12], q3.x, g1);
        g0 = fmaf(Ef[13], p3.y, g0); g1 = fmaf(Ef[13], q3.y, g1);
        g0 = fmaf(Ef[14], p3.z, g0); g1 = fmaf(Ef[14], q3.z, g1);
        g0 = fmaf(Ef[15], p3.w, g0); g1 = fmaf(Ef[15], q3.w, g1);

        v = fmaf(leaky(g0), as[2 * j],     v);
        v = fmaf(leaky(g1), as[2 * j + 1], v);
    }

    const float p = __expf(v);
    const int pos = atomicAdd(rowpos + d, 1);
    SP[pos] = make_int2(s, __float_as_int(p));
}

// ---------------- Kernel 3: per-node CSR aggregation + normalize + bias --------
__global__ __launch_bounds__(256) void agg_kernel(
    const ushort16* __restrict__ xtb, const int2* __restrict__ SP,
    const int* __restrict__ rowend, const float* __restrict__ bias,
    float* __restrict__ out, int N_)
{
    const int n    = blockIdx.x * 4 + (threadIdx.x >> 6);
    const int lane = threadIdx.x & 63;
    if (n >= N_) return;
    const int half = lane >> 5;
    const int c    = lane & 31;

    const int end   = rowend[n];
    const int start = n ? rowend[n - 1] : 0;
    const uint32* X = (const uint32*)xtb;    // dword idx = row*32 + c

    float accx = 0.f, accy = 0.f, den = 0.f;
    int i = start;
    for (; i + 7 < end; i += 8) {
        int2 A0 = SP[i+0], A1 = SP[i+1], A2 = SP[i+2], A3 = SP[i+3];
        int2 A4 = SP[i+4], A5 = SP[i+5], A6 = SP[i+6], A7 = SP[i+7];
        int   r0 = half ? A1.x : A0.x;  float p0 = __int_as_float(half ? A1.y : A0.y);
        int   r1 = half ? A3.x : A2.x;  float p1 = __int_as_float(half ? A3.y : A2.y);
        int   r2 = half ? A5.x : A4.x;  float p2 = __int_as_float(half ? A5.y : A4.y);
        int   r3 = half ? A7.x : A6.x;  float p3 = __int_as_float(half ? A7.y : A6.y);
        uint32 u0 = X[(size_t)r0 * 32 + c];
        uint32 u1 = X[(size_t)r1 * 32 + c];
        uint32 u2 = X[(size_t)r2 * 32 + c];
        uint32 u3 = X[(size_t)r3 * 32 + c];
        accx = fmaf(p0, bf_lo(u0), accx); accy = fmaf(p0, bf_hi(u0), accy);
        accx = fmaf(p1, bf_lo(u1), accx); accy = fmaf(p1, bf_hi(u1), accy);
        accx = fmaf(p2, bf_lo(u2), accx); accy = fmaf(p2, bf_hi(u2), accy);
        accx = fmaf(p3, bf_lo(u3), accx); accy = fmaf(p3, bf_hi(u3), accy);
        den += (p0 + p1) + (p2 + p3);
    }
    for (; i < end; i++) {                 // <=7 leftovers: low half only
        int2 a = SP[i];
        if (half == 0) {
            float p = __int_as_float(a.y);
            uint32 u = X[(size_t)a.x * 32 + c];
            accx = fmaf(p, bf_lo(u), accx);
            accy = fmaf(p, bf_hi(u), accy);
            den += p;
        }
    }
    accx += __shfl_xor(accx, 32, 64);
    accy += __shfl_xor(accy, 32, 64);
    den  += __shfl_xor(den,  32, 64);

    if (half == 0) {
        const float sc = den > 0.f ? 1.f / den : 0.f;
        const float2 bb = *(const float2*)(bias + 2 * c);
        float2 o;
        o.x = fmaf(accx, sc, bb.x);
        o.y = fmaf(accy, sc, bb.y);
        *(float2*)(out + (size_t)n * D + 2 * c) = o;
    }
}

extern "C" void kernel_launch(void* const* d_in, const int* in_sizes, int n_in,
                              void* d_out, int out_size, void* d_ws, size_t ws_size,
                              hipStream_t stream)
{
    const float* x         = (const float*)d_in[0];
    const float* edge_attr = (const float*)d_in[1];
    const int*   src       = (const int*)d_in[2];
    const int*   dst       = (const int*)d_in[3];
    const float* W1        = (const float*)d_in[4];
    const float* W2        = (const float*)d_in[5];
    const float* attn      = (const float*)d_in[6];
    const float* bias      = (const float*)d_in[7];
    float* out = (float*)d_out;

    const int N_ = in_sizes[0] / D;   // 100000
    const int E_ = in_sizes[2];       // 1280000

    // workspace (~36.7 MB):
    //   Abf[N*64] bf16 | xtb[N*64] bf16 | SP[E] int2 | rowst[N] | cnt[N] | part[256]
    char* w = (char*)d_ws;
    ushort16* Abf  = (ushort16*)w;  w += (size_t)N_ * D * sizeof(ushort16);
    ushort16* xtb  = (ushort16*)w;  w += (size_t)N_ * D * sizeof(ushort16);
    int2*     SP   = (int2*)w;      w += (size_t)E_ * sizeof(int2);
    int*      rowst= (int*)w;       w += (size_t)N_ * sizeof(int);
    int*      cnt  = (int*)w;       w += (size_t)N_ * sizeof(int);
    int*      part = (int*)w;

    hipMemsetAsync(cnt, 0, (size_t)N_ * sizeof(int), stream);

    const int NB1 = (N_ + 1023) / 1024;   // 98 (<=256 supported by scan2)

    hist_kernel<<<(E_ + 255) / 256, 256, 0, stream>>>(dst, cnt, E_);
    scan1<<<NB1, 256, 0, stream>>>(cnt, part, N_);
    scan2<<<1, 256, 0, stream>>>(part, NB1);
    scan3<<<NB1, 256, 0, stream>>>(cnt, part, rowst, N_);

    node_kernel<<<(N_ + 63) / 64, 256, 0, stream>>>(x, W1, W2, Abf, xtb, N_);

    edge_kernel<<<(E_ + 255) / 256, 256, 0, stream>>>(edge_attr, src, dst, W1,
                                                      attn, Abf, rowst, SP, E_);

    agg_kernel<<<(N_ + 3) / 4, 256, 0, stream>>>(xtb, SP, rowst, bias, out, N_);
}

// Round 8
// 412.220 us; speedup vs baseline: 1.3985x; 1.0342x over previous
//
#include <hip/hip_runtime.h>

#define D 64          // D_IN == D_OUT
#define D_EDGE 16
#define NEG 0.01f

typedef unsigned int  uint32;
typedef unsigned short ushort16;

// leaky = max(t, 0.01t): exact for both signs, 2 VALU ops
__device__ __forceinline__ float leaky(float v) { return fmaxf(v, NEG * v); }

// fp32 -> bf16 (round-to-nearest-even), and back (exact)
__device__ __forceinline__ ushort16 f2bf(float f) {
    uint32 b = __float_as_uint(f);
    uint32 r = b + 0x7fffu + ((b >> 16) & 1u);
    return (ushort16)(r >> 16);
}
__device__ __forceinline__ float bf2f(ushort16 u) {
    return __uint_as_float(((uint32)u) << 16);
}
__device__ __forceinline__ float bf_lo(uint32 w) { return __uint_as_float(w << 16); }
__device__ __forceinline__ float bf_hi(uint32 w) { return __uint_as_float(w & 0xffff0000u); }

// ---------------- Kernel 1: per-node precompute ----------------
//   xt[n] (bf16) = x[n] @ W2.T ; A[n] (bf16) = x[n] @ W1[:, :64].T
//   W rows wave-uniform (scalar loads); x staged coalesced via LDS; results
//   staged in LDS (stride-33) and written out coalesced (fixes the 20x HBM
//   write amplification measured in round 3: WRITE 523 MB -> ~26 MB).
__global__ __launch_bounds__(256) void node_kernel(
    const float* __restrict__ x, const float* __restrict__ W1,
    const float* __restrict__ W2,
    ushort16* __restrict__ Abf, ushort16* __restrict__ xtb, int N_)
{
    __shared__ float xs[64][68];               // 17408 B; reused for output staging
    uint32* sA = (uint32*)&xs[0][0];           // 64*33 dwords  (A = W1 part)
    uint32* sX = sA + 64 * 33;                 // 64*33 dwords  (xt = W2 part)

    const int tid = threadIdx.x;
    const int b0  = blockIdx.x * 64;

    // coalesced stage: 64 rows x 16 float4
    for (int idx = tid; idx < 64 * 16; idx += 256) {
        const int rr = idx >> 4, cc = idx & 15;
        float4 v = make_float4(0.f, 0.f, 0.f, 0.f);
        if (b0 + rr < N_) v = ((const float4*)(x + (size_t)(b0 + rr) * D))[cc];
        *(float4*)&xs[rr][cc * 4] = v;
    }
    __syncthreads();

    const int lane = tid & 63;
    const int q    = __builtin_amdgcn_readfirstlane(tid >> 6);   // wave-uniform

    float4 xr[16];
#pragma unroll
    for (int i = 0; i < 16; i++) xr[i] = *(const float4*)&xs[lane][4 * i];
    __syncthreads();    // xs re-used as sA/sX below; all reads must be done

    float a_prev = 0.f, b_prev = 0.f;
#pragma unroll
    for (int kk = 0; kk < 16; kk++) {
        const int k = q * 16 + kk;
        const float4* w2r = (const float4*)(W2 + (size_t)k * 64);   // uniform -> s_load
        const float4* w1r = (const float4*)(W1 + (size_t)k * 80);
        float a = 0.f, b = 0.f;
#pragma unroll
        for (int j = 0; j < 16; j++) {
            float4 w = w2r[j];
            a += xr[j].x * w.x + xr[j].y * w.y + xr[j].z * w.z + xr[j].w * w.w;
            float4 u = w1r[j];
            b += xr[j].x * u.x + xr[j].y * u.y + xr[j].z * u.z + xr[j].w * u.w;
        }
        if (kk & 1) {
            const int pr = k >> 1;    // global dword col 0..31
            sX[lane * 33 + pr] = (uint32)f2bf(a_prev) | ((uint32)f2bf(a) << 16);
            sA[lane * 33 + pr] = (uint32)f2bf(b_prev) | ((uint32)f2bf(b) << 16);
        } else {
            a_prev = a; b_prev = b;
        }
    }
    __syncthreads();

    // coalesced writeout
    uint32* Au = (uint32*)Abf;
    uint32* Xu = (uint32*)xtb;
    const size_t gbase = (size_t)b0 * 32;
    for (int base = tid * 4; base < 2048; base += 1024) {
        const int nn = base >> 5, cc = base & 31;
        if (b0 + nn < N_) {
            const uint32* ra = sA + nn * 33 + cc;
            const uint32* rx = sX + nn * 33 + cc;
            uint4 va = make_uint4(ra[0], ra[1], ra[2], ra[3]);
            uint4 vx = make_uint4(rx[0], rx[1], rx[2], rx[3]);
            *(uint4*)(Au + gbase + base) = va;
            *(uint4*)(Xu + gbase + base) = vx;
        }
    }
}

// ---------------- CSR build: histogram + 2-kernel exclusive scan ----------------
__global__ __launch_bounds__(256) void hist_kernel(
    const int* __restrict__ dst, int* __restrict__ cnt, int E_)
{
    int i = blockIdx.x * 256 + threadIdx.x;
    if (i < E_) atomicAdd(cnt + dst[i], 1);
}

// block b reduces cnt[b*1024 .. +1023] -> part[b] (raw block sums)
__global__ __launch_bounds__(256) void scan1(
    const int* __restrict__ cnt, int* __restrict__ part, int N_)
{
    __shared__ int sm[256];
    const int b = blockIdx.x, t = threadIdx.x;
    const int i0 = b * 1024 + t * 4;
    int s = 0;
    if (i0     < N_) s += cnt[i0];
    if (i0 + 1 < N_) s += cnt[i0 + 1];
    if (i0 + 2 < N_) s += cnt[i0 + 2];
    if (i0 + 3 < N_) s += cnt[i0 + 3];
    sm[t] = s; __syncthreads();
    for (int off = 128; off > 0; off >>= 1) {
        if (t < off) sm[t] += sm[t + off];
        __syncthreads();
    }
    if (t == 0) part[b] = sm[0];
}

// block b: scans RAW part[] itself in LDS (nb<=256, L2-hot) -> base, then
// writes exclusive prefix of its 1024 cnt's. (scan2 folded in: -1 dispatch)
__global__ __launch_bounds__(256) void scan3(
    const int* __restrict__ cnt, const int* __restrict__ part,
    int* __restrict__ rowst, int N_, int nb)
{
    __shared__ int sp[256];
    __shared__ int sm[256];
    const int b = blockIdx.x, t = threadIdx.x;

    sp[t] = (t < nb) ? part[t] : 0;
    __syncthreads();
    for (int off = 1; off < 256; off <<= 1) {    // inclusive scan of partials
        int a = (t >= off) ? sp[t - off] : 0;
        __syncthreads();
        sp[t] += a;
        __syncthreads();
    }
    const int pbase = (b > 0) ? sp[b - 1] : 0;

    const int i0 = b * 1024 + t * 4;
    int c0 = 0, c1 = 0, c2 = 0, c3 = 0;
    if (i0     < N_) c0 = cnt[i0];
    if (i0 + 1 < N_) c1 = cnt[i0 + 1];
    if (i0 + 2 < N_) c2 = cnt[i0 + 2];
    if (i0 + 3 < N_) c3 = cnt[i0 + 3];
    const int s = c0 + c1 + c2 + c3;
    sm[t] = s; __syncthreads();
    for (int off = 1; off < 256; off <<= 1) {
        int a = (t >= off) ? sm[t - off] : 0;
        __syncthreads();
        sm[t] += a;
        __syncthreads();
    }
    const int base = pbase + (sm[t] - s);
    if (i0     < N_) rowst[i0]     = base;
    if (i0 + 1 < N_) rowst[i0 + 1] = base + c0;
    if (i0 + 2 < N_) rowst[i0 + 2] = base + c0 + c1;
    if (i0 + 3 < N_) rowst[i0 + 3] = base + c0 + c1 + c2;
}

// ---------------- Kernel 2: edge logits, ONE LANE PER EDGE ----------------
// Round-4 structure (scalar weight loads from flat W1 — 118 us proven; LDS
// variant was 133 us + 2x FETCH, reverted). NEW: each 16-term dot split into
// TWO independent 8-term FMA chains (+1 add), v split into va/vb — raises
// independent chains 2->6 so issue slots fill instead of waiting out the
// 4-6 cy FMA latency (round-4 VALUBusy 35% = dep-chain-limited signature).
// __launch_bounds__(256,4) lifts the VGPR cap so the scheduler can interleave.
__global__ __launch_bounds__(256, 4) void edge_kernel(
    const float* __restrict__ edge_attr, const int* __restrict__ src,
    const int* __restrict__ dst, const float* __restrict__ W1,
    const float* __restrict__ attn, const ushort16* __restrict__ Abf,
    int* __restrict__ rowpos, int2* __restrict__ SP, int E_)
{
    const int e = blockIdx.x * 256 + threadIdx.x;
    if (e >= E_) return;

    const int s = src[e];
    const int d = dst[e];

    // this lane's A row: 64 bf16 = 32 packed dwords (128 B = 1 line), gather
    uint32 Ad[32];
    {
        const uint4* Ap = (const uint4*)(Abf + (size_t)s * D);
#pragma unroll
        for (int i = 0; i < 8; i++) *(uint4*)(Ad + 4 * i) = Ap[i];
    }
    // this lane's edge_attr row: 16 f32 (64 B), dense across lanes
    float Ef[16];
    {
        const float4* Ep = (const float4*)(edge_attr + (size_t)e * D_EDGE);
#pragma unroll
        for (int i = 0; i < 4; i++) *(float4*)(Ef + 4 * i) = Ep[i];
    }

    float va = 0.f, vb = 0.f;
#pragma unroll
    for (int j = 0; j < 32; ++j) {          // packed dword j -> channels 2j, 2j+1
        // wave-uniform weight rows (16B-aligned): scalar loads
        const float4* w0 = (const float4*)(W1 + (2 * j) * 80 + 64);
        const float4* w1 = (const float4*)(W1 + (2 * j + 1) * 80 + 64);
        float4 p0 = w0[0], p1 = w0[1], p2 = w0[2], p3 = w0[3];
        float4 q0 = w1[0], q1 = w1[1], q2 = w1[2], q3 = w1[3];

        // channel 2j: two independent 8-term chains
        float c0 = bf_lo(Ad[j]);
        float c1 = 0.f;
        c0 = fmaf(Ef[ 0], p0.x, c0); c1 = fmaf(Ef[ 8], p2.x, c1);
        c0 = fmaf(Ef[ 1], p0.y, c0); c1 = fmaf(Ef[ 9], p2.y, c1);
        c0 = fmaf(Ef[ 2], p0.z, c0); c1 = fmaf(Ef[10], p2.z, c1);
        c0 = fmaf(Ef[ 3], p0.w, c0); c1 = fmaf(Ef[11], p2.w, c1);
        c0 = fmaf(Ef[ 4], p1.x, c0); c1 = fmaf(Ef[12], p3.x, c1);
        c0 = fmaf(Ef[ 5], p1.y, c0); c1 = fmaf(Ef[13], p3.y, c1);
        c0 = fmaf(Ef[ 6], p1.z, c0); c1 = fmaf(Ef[14], p3.z, c1);
        c0 = fmaf(Ef[ 7], p1.w, c0); c1 = fmaf(Ef[15], p3.w, c1);
        float g0 = c0 + c1;

        // channel 2j+1: two more independent chains
        float e0 = bf_hi(Ad[j]);
        float e1 = 0.f;
        e0 = fmaf(Ef[ 0], q0.x, e0); e1 = fmaf(Ef[ 8], q2.x, e1);
        e0 = fmaf(Ef[ 1], q0.y, e0); e1 = fmaf(Ef[ 9], q2.y, e1);
        e0 = fmaf(Ef[ 2], q0.z, e0); e1 = fmaf(Ef[10], q2.z, e1);
        e0 = fmaf(Ef[ 3], q0.w, e0); e1 = fmaf(Ef[11], q2.w, e1);
        e0 = fmaf(Ef[ 4], q1.x, e0); e1 = fmaf(Ef[12], q3.x, e1);
        e0 = fmaf(Ef[ 5], q1.y, e0); e1 = fmaf(Ef[13], q3.y, e1);
        e0 = fmaf(Ef[ 6], q1.z, e0); e1 = fmaf(Ef[14], q3.z, e1);
        e0 = fmaf(Ef[ 7], q1.w, e0); e1 = fmaf(Ef[15], q3.w, e1);
        float g1 = e0 + e1;

        va = fmaf(leaky(g0), attn[2 * j],     va);
        vb = fmaf(leaky(g1), attn[2 * j + 1], vb);
    }

    const float p = __expf(va + vb);
    const int pos = atomicAdd(rowpos + d, 1);
    SP[pos] = make_int2(s, __float_as_int(p));
}

// ---------------- Kernel 3: per-node CSR aggregation + normalize + bias --------
__global__ __launch_bounds__(256) void agg_kernel(
    const ushort16* __restrict__ xtb, const int2* __restrict__ SP,
    const int* __restrict__ rowend, const float* __restrict__ bias,
    float* __restrict__ out, int N_)
{
    const int n    = blockIdx.x * 4 + (threadIdx.x >> 6);
    const int lane = threadIdx.x & 63;
    if (n >= N_) return;
    const int half = lane >> 5;
    const int c    = lane & 31;

    const int end   = rowend[n];
    const int start = n ? rowend[n - 1] : 0;
    const uint32* X = (const uint32*)xtb;    // dword idx = row*32 + c

    float accx = 0.f, accy = 0.f, den = 0.f;
    int i = start;
    for (; i + 7 < end; i += 8) {
        int2 A0 = SP[i+0], A1 = SP[i+1], A2 = SP[i+2], A3 = SP[i+3];
        int2 A4 = SP[i+4], A5 = SP[i+5], A6 = SP[i+6], A7 = SP[i+7];
        int   r0 = half ? A1.x : A0.x;  float p0 = __int_as_float(half ? A1.y : A0.y);
        int   r1 = half ? A3.x : A2.x;  float p1 = __int_as_float(half ? A3.y : A2.y);
        int   r2 = half ? A5.x : A4.x;  float p2 = __int_as_float(half ? A5.y : A4.y);
        int   r3 = half ? A7.x : A6.x;  float p3 = __int_as_float(half ? A7.y : A6.y);
        uint32 u0 = X[(size_t)r0 * 32 + c];
        uint32 u1 = X[(size_t)r1 * 32 + c];
        uint32 u2 = X[(size_t)r2 * 32 + c];
        uint32 u3 = X[(size_t)r3 * 32 + c];
        accx = fmaf(p0, bf_lo(u0), accx); accy = fmaf(p0, bf_hi(u0), accy);
        accx = fmaf(p1, bf_lo(u1), accx); accy = fmaf(p1, bf_hi(u1), accy);
        accx = fmaf(p2, bf_lo(u2), accx); accy = fmaf(p2, bf_hi(u2), accy);
        accx = fmaf(p3, bf_lo(u3), accx); accy = fmaf(p3, bf_hi(u3), accy);
        den += (p0 + p1) + (p2 + p3);
    }
    for (; i < end; i++) {                 // <=7 leftovers: low half only
        int2 a = SP[i];
        if (half == 0) {
            float p = __int_as_float(a.y);
            uint32 u = X[(size_t)a.x * 32 + c];
            accx = fmaf(p, bf_lo(u), accx);
            accy = fmaf(p, bf_hi(u), accy);
            den += p;
        }
    }
    accx += __shfl_xor(accx, 32, 64);
    accy += __shfl_xor(accy, 32, 64);
    den  += __shfl_xor(den,  32, 64);

    if (half == 0) {
        const float sc = den > 0.f ? 1.f / den : 0.f;
        const float2 bb = *(const float2*)(bias + 2 * c);
        float2 o;
        o.x = fmaf(accx, sc, bb.x);
        o.y = fmaf(accy, sc, bb.y);
        *(float2*)(out + (size_t)n * D + 2 * c) = o;
    }
}

extern "C" void kernel_launch(void* const* d_in, const int* in_sizes, int n_in,
                              void* d_out, int out_size, void* d_ws, size_t ws_size,
                              hipStream_t stream)
{
    const float* x         = (const float*)d_in[0];
    const float* edge_attr = (const float*)d_in[1];
    const int*   src       = (const int*)d_in[2];
    const int*   dst       = (const int*)d_in[3];
    const float* W1        = (const float*)d_in[4];
    const float* W2        = (const float*)d_in[5];
    const float* attn      = (const float*)d_in[6];
    const float* bias      = (const float*)d_in[7];
    float* out = (float*)d_out;

    const int N_ = in_sizes[0] / D;   // 100000
    const int E_ = in_sizes[2];       // 1280000

    // workspace (~36.7 MB):
    //   Abf[N*64] bf16 | xtb[N*64] bf16 | SP[E] int2 | rowst[N] | cnt[N] | part[256]
    char* w = (char*)d_ws;
    ushort16* Abf  = (ushort16*)w;  w += (size_t)N_ * D * sizeof(ushort16);
    ushort16* xtb  = (ushort16*)w;  w += (size_t)N_ * D * sizeof(ushort16);
    int2*     SP   = (int2*)w;      w += (size_t)E_ * sizeof(int2);
    int*      rowst= (int*)w;       w += (size_t)N_ * sizeof(int);
    int*      cnt  = (int*)w;       w += (size_t)N_ * sizeof(int);
    int*      part = (int*)w;

    hipMemsetAsync(cnt, 0, (size_t)N_ * sizeof(int), stream);

    const int NB1 = (N_ + 1023) / 1024;   // 98 (<=256 supported)

    hist_kernel<<<(E_ + 255) / 256, 256, 0, stream>>>(dst, cnt, E_);
    scan1<<<NB1, 256, 0, stream>>>(cnt, part, N_);
    scan3<<<NB1, 256, 0, stream>>>(cnt, part, rowst, N_, NB1);

    node_kernel<<<(N_ + 63) / 64, 256, 0, stream>>>(x, W1, W2, Abf, xtb, N_);

    edge_kernel<<<(E_ + 255) / 256, 256, 0, stream>>>(edge_attr, src, dst, W1,
                                                      attn, Abf, rowst, SP, E_);

    agg_kernel<<<(N_ + 3) / 4, 256, 0, stream>>>(xtb, SP, rowst, bias, out, N_);
}